// Round 12
// baseline (3293.477 us; speedup 1.0000x reference)
//
#include <hip/hip_runtime.h>
#include <math.h>

#define B_    4096
#define A_    6
#define V_    1024
#define L_    32
#define DIN_  64
#define DOUT_ 64
#define H_    512
#define AD    384          // A_*DIN_

typedef unsigned short us;
typedef __attribute__((ext_vector_type(8))) short short8;   // 8 bf16
typedef __attribute__((ext_vector_type(4))) float f32x4;

static constexpr size_t GW_HALF = 128ull * 18 * 512;   // us per split (gates)
static constexpr size_t LW_HALF = 64ull  * 16 * 512;   // us per split (logits)
static constexpr size_t HPLANE  = 4096ull * 512;       // us per h plane

// ---- bf16 helpers (RNE) ----
__device__ __forceinline__ us bfhi(float v) {
  union { float f; unsigned u; } a; a.f = v;
  unsigned r = a.u + 0x7FFFu + ((a.u >> 16) & 1u);
  return (us)(r >> 16);
}
__device__ __forceinline__ float bf2f(us s) {
  union { unsigned u; float f; } a; a.u = (unsigned)s << 16;
  return a.f;
}
__device__ __forceinline__ void bfsplit(float v, us& hi, us& lo) {
  hi = bfhi(v);
  lo = bfhi(v - bf2f(hi));
}
__device__ __forceinline__ int swzE(int m, int k) { return m * 64 + (k ^ ((m & 7) << 3)); }

// async global->LDS, 16B per lane; dest = uniform base + lane*16
__device__ __forceinline__ void gl_lds16(const us* g, us* l) {
  __builtin_amdgcn_global_load_lds(
      (const __attribute__((address_space(1))) unsigned int*)g,
      (__attribute__((address_space(3))) unsigned int*)l, 16, 0, 0);
}

#define MFMA(A, Bv, C) __builtin_amdgcn_mfma_f32_16x16x32_bf16((A), (Bv), (C), 0, 0, 0)

// ---- pack gates: tile = ((js*4+g)*8+jn), kt 0..17 (16 h + 2 emb); kappa(l,e)=(l>>4)*8+e ----
__global__ void pack_gw(const float* __restrict__ W_ih, const float* __restrict__ W_hh,
                        us* __restrict__ WgB) {
  int idx  = blockIdx.x * 256 + threadIdx.x;   // < 128*18*64
  int lane = idx & 63;
  int kt   = (idx >> 6) % 18;
  int tile = idx / (18 * 64);                  // 0..127
  int jn = tile & 7, g = (tile >> 3) & 3, js = tile >> 5;
  int l15 = lane & 15, lg = lane >> 4;
  int gcol = g * 512 + js * 128 + jn * 16 + l15;
  size_t bh = ((size_t)tile * 18 + kt) * 512 + (size_t)lane * 8;
  #pragma unroll
  for (int e = 0; e < 8; e++) {
    int kk = lg * 8 + e;
    float v = (kt < 16) ? W_hh[(size_t)gcol * H_ + kt * 32 + kk]
                        : W_ih[(size_t)gcol * DOUT_ + (kt - 16) * 32 + kk];
    us hi, lo; bfsplit(v, hi, lo);
    WgB[bh + e]           = hi;
    WgB[GW_HALF + bh + e] = lo;
  }
}

// ---- pack Wo[512][1024] -> B-frag tiles (verified layout, vb linear) ----
__global__ void pack_lw(const float* __restrict__ Wo, us* __restrict__ WoB) {
  int idx = blockIdx.x * 256 + threadIdx.x;    // < 64*16*64
  int lane = idx & 63;
  int kt = (idx >> 6) % 16;
  int vb = idx / (16 * 64);
  int l15 = lane & 15, lg = lane >> 4;
  int n = vb * 16 + l15;
  size_t bh = ((size_t)vb * 16 + kt) * 512 + (size_t)lane * 8;
  #pragma unroll
  for (int e = 0; e < 8; e++) {
    int k = kt * 32 + lg * 8 + e;
    us hi, lo; bfsplit(Wo[(size_t)k * V_ + n], hi, lo);
    WoB[bh + e]           = hi;
    WoB[LW_HALF + bh + e] = lo;
  }
}

// ---- prologue: h0 = e @ Wi + bi -> plane0 (bf16 split) ----
__global__ void h0_kernel(const int* __restrict__ x, const float* __restrict__ input_emb,
                          const float* __restrict__ Wi, const float* __restrict__ bi,
                          us* __restrict__ h_hi, us* __restrict__ h_lo) {
  __shared__ float sbuf[16 * AD];
  const int t = threadIdx.x, r0 = blockIdx.x * 16;
  for (int idx = t; idx < 16 * AD; idx += 1024) {
    int r = idx / AD, rem = idx - r * AD;
    sbuf[idx] = input_emb[x[(r0 + r) * A_ + (rem >> 6)] * DIN_ + (rem & 63)];
  }
  __syncthreads();
  int j = t & 511, half = t >> 9;
  float acc[8];
  #pragma unroll
  for (int r = 0; r < 8; r++) acc[r] = 0.f;
  for (int k = 0; k < AD; k++) {
    float wv = Wi[(size_t)k * H_ + j];
    #pragma unroll
    for (int r = 0; r < 8; r++)
      acc[r] = fmaf(sbuf[(half * 8 + r) * AD + k], wv, acc[r]);
  }
  float bj = bi[j];
  #pragma unroll
  for (int r = 0; r < 8; r++) {
    int row = r0 + half * 8 + r;
    us hi, lo; bfsplit(acc[r] + bj, hi, lo);
    h_hi[(size_t)row * H_ + j] = hi;
    h_lo[(size_t)row * H_ + j] = lo;
  }
}

// ---- gates + cell: grid 256 = rg(64) x js(4); block 64 rows x 512 gate-cols ----
// R12 wave mapping (2 mt x 4 gate-tiles): mtp=w&1 -> rows mtp*32..+31,
// cq=w>>1 -> col slice cq*16..+15 across all 4 gates. Halves B LDS reads
// (16 -> 8 per wave per kt); A-side redundancy moves to L1/VMEM (overlaps stage).
__launch_bounds__(1024)
__global__ void g_step(
    const us* __restrict__ hin_hi, const us* __restrict__ hin_lo,
    us* __restrict__ hout_hi, us* __restrict__ hout_lo,
    float* __restrict__ cst,
    const float* __restrict__ cand_v, const int* __restrict__ cand_i,
    const float* __restrict__ output_emb, const float* __restrict__ sos,
    const float* __restrict__ b_ih, const float* __restrict__ b_hh,
    const us* __restrict__ WgB,
    float* __restrict__ out_seq, int step)
{
  __shared__ __align__(16) us ldsB[2][32][2][512];   // 128 KB (dbuf x tile x half)
  __shared__ __align__(16) us seA_hi[64 * 64];       // 8 KB
  __shared__ __align__(16) us seA_lo[64 * 64];       // 8 KB

  const int t = threadIdx.x, lane = t & 63, w = t >> 6;
  const int l15 = lane & 15, lg = lane >> 4;
  const int rg = blockIdx.x >> 2, js = blockIdx.x & 3;
  const int r0 = rg * 64;
  const int mtp = w & 1, cq = w >> 1;

  // ---- stage kt=0 into buf 0 (each wave: chunks 4w..4w+3) ----
  #pragma unroll
  for (int q = 0; q < 4; q++) {
    int c = w * 4 + q, tl = c >> 1, half = c & 1;
    const us* src = WgB + (size_t)half * GW_HALF
                  + ((size_t)(js * 32 + tl) * 18 + 0) * 512 + (size_t)lane * 8;
    gl_lds16(src, &ldsB[0][tl][half][(size_t)lane * 8]);
  }

  // ---- prologue: winner-merge (step>0) + emb stage ----
  {
    int row = t >> 4;            // 0..63
    int d0  = (t & 15) * 4;
    if (step == 0) {
      #pragma unroll
      for (int dd = 0; dd < 4; dd++) {
        int d = d0 + dd;
        us hi, lo; bfsplit(sos[d], hi, lo);
        int si = swzE(row, d);
        seA_hi[si] = hi; seA_lo[si] = lo;
      }
    } else {
      int grow = r0 + row;
      float bv = cand_v[grow * 4 + 0];
      int   bx = cand_i[grow * 4 + 0];
      #pragma unroll
      for (int c = 1; c < 4; c++) {
        float ov = cand_v[grow * 4 + c];
        int   ox = cand_i[grow * 4 + c];
        if (ov > bv || (ov == bv && ox < bx)) { bv = ov; bx = ox; }
      }
      if (js == 0 && (t & 15) == 0)
        out_seq[(size_t)grow * L_ + (step - 1)] = (float)bx;
      #pragma unroll
      for (int dd = 0; dd < 4; dd++) {
        int d = d0 + dd;
        us hi, lo; bfsplit(output_emb[(size_t)bx * DOUT_ + d], hi, lo);
        int si = swzE(row, d);
        seA_hi[si] = hi; seA_lo[si] = lo;
      }
    }
  }
  __syncthreads();   // seA ready; stage(kt=0) drained (barrier waits vmcnt 0)

  // ---- bias init: acc[mi][g], cols g*512 + js*128 + cq*16 + l15 ----
  f32x4 acc[2][4];
  #pragma unroll
  for (int g = 0; g < 4; g++) {
    int col = g * 512 + js * 128 + cq * 16 + l15;
    float b = b_ih[col] + b_hh[col];
    acc[0][g] = (f32x4){b, b, b, b};
    acc[1][g] = (f32x4){b, b, b, b};
  }

  const size_t arow0 = (size_t)(r0 + mtp * 32 + l15) * H_;        // mi=0 tile rows
  const size_t arow1 = (size_t)(r0 + mtp * 32 + 16 + l15) * H_;   // mi=1 tile rows
  for (int kt = 0; kt < 18; kt++) {
    const int buf = kt & 1;
    if (kt + 1 < 18) {
      #pragma unroll
      for (int q = 0; q < 4; q++) {
        int c = w * 4 + q, tl = c >> 1, half = c & 1;
        const us* src = WgB + (size_t)half * GW_HALF
                      + ((size_t)(js * 32 + tl) * 18 + (kt + 1)) * 512 + (size_t)lane * 8;
        gl_lds16(src, &ldsB[buf ^ 1][tl][half][(size_t)lane * 8]);
      }
    }
    short8 Ah[2], Al[2];
    if (kt < 16) {
      size_t ko = (size_t)kt * 32 + lg * 8;
      Ah[0] = *(const short8*)(hin_hi + arow0 + ko);
      Al[0] = *(const short8*)(hin_lo + arow0 + ko);
      Ah[1] = *(const short8*)(hin_hi + arow1 + ko);
      Al[1] = *(const short8*)(hin_lo + arow1 + ko);
    } else {
      int k0 = (kt - 16) * 32 + lg * 8;
      int ai0 = swzE(mtp * 32 + l15, k0);
      int ai1 = swzE(mtp * 32 + 16 + l15, k0);
      Ah[0] = *(const short8*)&seA_hi[ai0];
      Al[0] = *(const short8*)&seA_lo[ai0];
      Ah[1] = *(const short8*)&seA_hi[ai1];
      Al[1] = *(const short8*)&seA_lo[ai1];
    }
    #pragma unroll
    for (int g = 0; g < 4; g++) {
      int tl = g * 8 + cq;
      short8 Bh = *(const short8*)&ldsB[buf][tl][0][(size_t)lane * 8];
      short8 Bl = *(const short8*)&ldsB[buf][tl][1][(size_t)lane * 8];
      #pragma unroll
      for (int mi = 0; mi < 2; mi++) {
        acc[mi][g] = MFMA(Ah[mi], Bh, acc[mi][g]);
        acc[mi][g] = MFMA(Al[mi], Bh, acc[mi][g]);
        acc[mi][g] = MFMA(Ah[mi], Bl, acc[mi][g]);
      }
    }
    __syncthreads();   // readers done with buf; stage(kt+1) complete
  }

  // ---- cell update: row = r0+mtp*32+mi*16+lg*4+reg, j = js*128+cq*16+l15 ----
  const int j = js * 128 + cq * 16 + l15;
  #pragma unroll
  for (int mi = 0; mi < 2; mi++)
    #pragma unroll
    for (int reg = 0; reg < 4; reg++) {
      int row = r0 + mtp * 32 + mi * 16 + lg * 4 + reg;
      size_t cix = (size_t)row * H_ + j;
      float cprev = (step == 0) ? 0.f : cst[cix];
      float iv = 1.f / (1.f + expf(-acc[mi][0][reg]));
      float fv = 1.f / (1.f + expf(-acc[mi][1][reg]));
      float gv = tanhf(acc[mi][2][reg]);
      float ov = 1.f / (1.f + expf(-acc[mi][3][reg]));
      float cn = fv * cprev + iv * gv;
      cst[cix] = cn;
      us hi, lo; bfsplit(ov * tanhf(cn), hi, lo);
      hout_hi[cix] = hi;
      hout_lo[cix] = lo;
    }
}

// ---- logits + partial argmax: grid 256 = rg(64) x vs(4); block 64 rows x 256 vocab ----
// R12 wave mapping (2 mt x 2 vt): mtp=w&1 -> rows mtp*32..+31, vq=w>>1 -> cols vq*32..+31.
__launch_bounds__(1024)
__global__ void l_step(
    const us* __restrict__ h_hi, const us* __restrict__ h_lo,
    const us* __restrict__ WoB, const float* __restrict__ bo,
    float* __restrict__ out_logits,
    float* __restrict__ cand_v, int* __restrict__ cand_i, int step)
{
  __shared__ __align__(16) us ldsB2[2][16][2][512];  // 64 KB
  __shared__ float cv[64 * 8];
  __shared__ int   ci[64 * 8];

  const int t = threadIdx.x, lane = t & 63, w = t >> 6;
  const int l15 = lane & 15, lg = lane >> 4;
  const int rg = blockIdx.x >> 2, vs = blockIdx.x & 3;
  const int r0 = rg * 64;
  const int mtp = w & 1, vq = w >> 1;

  // stage kt=0 (each wave: chunks 2w..2w+1)
  #pragma unroll
  for (int q = 0; q < 2; q++) {
    int c = w * 2 + q, tl = c >> 1, half = c & 1;
    const us* src = WoB + (size_t)half * LW_HALF
                  + ((size_t)(vs * 16 + tl) * 16 + 0) * 512 + (size_t)lane * 8;
    gl_lds16(src, &ldsB2[0][tl][half][(size_t)lane * 8]);
  }
  __syncthreads();

  f32x4 acc[2][2];   // [mi][vt]
  #pragma unroll
  for (int vt = 0; vt < 2; vt++) {
    float b = bo[vs * 256 + vq * 32 + vt * 16 + l15];
    acc[0][vt] = (f32x4){b, b, b, b};
    acc[1][vt] = (f32x4){b, b, b, b};
  }

  const size_t arow0 = (size_t)(r0 + mtp * 32 + l15) * H_;
  const size_t arow1 = (size_t)(r0 + mtp * 32 + 16 + l15) * H_;
  for (int kt = 0; kt < 16; kt++) {
    const int buf = kt & 1;
    if (kt + 1 < 16) {
      #pragma unroll
      for (int q = 0; q < 2; q++) {
        int c = w * 2 + q, tl = c >> 1, half = c & 1;
        const us* src = WoB + (size_t)half * LW_HALF
                      + ((size_t)(vs * 16 + tl) * 16 + (kt + 1)) * 512 + (size_t)lane * 8;
        gl_lds16(src, &ldsB2[buf ^ 1][tl][half][(size_t)lane * 8]);
      }
    }
    size_t ko = (size_t)kt * 32 + lg * 8;
    short8 Ah[2], Al[2];
    Ah[0] = *(const short8*)(h_hi + arow0 + ko);
    Al[0] = *(const short8*)(h_lo + arow0 + ko);
    Ah[1] = *(const short8*)(h_hi + arow1 + ko);
    Al[1] = *(const short8*)(h_lo + arow1 + ko);
    #pragma unroll
    for (int vt = 0; vt < 2; vt++) {
      int tl = vq * 2 + vt;
      short8 Bh = *(const short8*)&ldsB2[buf][tl][0][(size_t)lane * 8];
      short8 Bl = *(const short8*)&ldsB2[buf][tl][1][(size_t)lane * 8];
      #pragma unroll
      for (int mi = 0; mi < 2; mi++) {
        acc[mi][vt] = MFMA(Ah[mi], Bh, acc[mi][vt]);
        acc[mi][vt] = MFMA(Al[mi], Bh, acc[mi][vt]);
        acc[mi][vt] = MFMA(Ah[mi], Bl, acc[mi][vt]);
      }
    }
    __syncthreads();
  }

  // ---- store logits + per-lane best over vt (ascending: first-index-wins) ----
  float bv[2][4]; int bx[2][4];
  #pragma unroll
  for (int mi = 0; mi < 2; mi++)
    #pragma unroll
    for (int reg = 0; reg < 4; reg++) {
      bv[mi][reg] = acc[mi][0][reg];
      bx[mi][reg] = vs * 256 + vq * 32 + l15;
    }
  #pragma unroll
  for (int vt = 0; vt < 2; vt++) {
    int col = vs * 256 + vq * 32 + vt * 16 + l15;
    #pragma unroll
    for (int mi = 0; mi < 2; mi++)
      #pragma unroll
      for (int reg = 0; reg < 4; reg++) {
        int row = r0 + mtp * 32 + mi * 16 + lg * 4 + reg;
        float vvl = acc[mi][vt][reg];
        __builtin_nontemporal_store(vvl, &out_logits[((size_t)row * L_ + step) * V_ + col]);
        if (vt > 0 && vvl > bv[mi][reg]) { bv[mi][reg] = vvl; bx[mi][reg] = col; }
      }
  }
  // reduce across the 16 l15 lanes (xor 1,2,4,8) — first-index-wins
  #pragma unroll
  for (int mi = 0; mi < 2; mi++)
    #pragma unroll
    for (int reg = 0; reg < 4; reg++) {
      float b2 = bv[mi][reg]; int x2 = bx[mi][reg];
      #pragma unroll
      for (int off = 1; off <= 8; off <<= 1) {
        float ov = __shfl_xor(b2, off);
        int   ox = __shfl_xor(x2, off);
        if (ov > b2 || (ov == b2 && ox < x2)) { b2 = ov; x2 = ox; }
      }
      if (l15 == 0) {
        int rloc = mtp * 32 + mi * 16 + lg * 4 + reg;
        cv[rloc * 8 + vq] = b2;
        ci[rloc * 8 + vq] = x2;
      }
    }
  __syncthreads();
  if (t < 64) {
    float b2 = cv[t * 8]; int x2 = ci[t * 8];
    #pragma unroll
    for (int c = 1; c < 8; c++) {
      float ov = cv[t * 8 + c]; int ox = ci[t * 8 + c];
      if (ov > b2 || (ov == b2 && ox < x2)) { b2 = ov; x2 = ox; }
    }
    cand_v[(size_t)(r0 + t) * 4 + vs] = b2;
    cand_i[(size_t)(r0 + t) * 4 + vs] = x2;
  }
}

// ---- final: merge step-31 candidates -> seq col 31 ----
__global__ void fin_kernel(const float* __restrict__ cand_v, const int* __restrict__ cand_i,
                           float* __restrict__ out_seq) {
  int row = blockIdx.x * 256 + threadIdx.x;
  float bv = cand_v[(size_t)row * 4];
  int   bx = cand_i[(size_t)row * 4];
  #pragma unroll
  for (int c = 1; c < 4; c++) {
    float ov = cand_v[(size_t)row * 4 + c];
    int   ox = cand_i[(size_t)row * 4 + c];
    if (ov > bv || (ov == bv && ox < bx)) { bv = ov; bx = ox; }
  }
  out_seq[(size_t)row * L_ + 31] = (float)bx;
}

// ---------------- fp32 single-kernel fallback (ws too small) ----------------
__launch_bounds__(1024)
__global__ void lstm_fb(
    const int* __restrict__ x, const float* __restrict__ input_emb,
    const float* __restrict__ output_emb, const float* __restrict__ Wi,
    const float* __restrict__ bi, const float* __restrict__ W_ih,
    const float* __restrict__ W_hh, const float* __restrict__ b_ih,
    const float* __restrict__ b_hh, const float* __restrict__ Wo,
    const float* __restrict__ bo, const float* __restrict__ sos,
    float* __restrict__ out)
{
  __shared__ __align__(16) float sh[16 * H_];
  __shared__ __align__(16) float semb[16 * DOUT_];
  __shared__ __align__(16) float sbuf[16 * AD];

  const int t = threadIdx.x, r0 = blockIdx.x * 16;
  const int j = t & 511, rbase = (t >> 9) * 8, wv = t >> 6;
  float* out_seq = out;
  float* out_logits = out + (size_t)B_ * L_;

  for (int idx = t; idx < 16 * AD; idx += 1024) {
    int r = idx / AD, rem = idx - r * AD;
    sbuf[idx] = input_emb[x[(r0 + r) * A_ + (rem >> 6)] * DIN_ + (rem & 63)];
  }
  for (int idx = t; idx < 16 * DOUT_; idx += 1024) semb[idx] = sos[idx & 63];
  __syncthreads();
  {
    float acc[8];
    #pragma unroll
    for (int r = 0; r < 8; r++) acc[r] = 0.f;
    for (int k = 0; k < AD; k++) {
      float wv2 = Wi[(size_t)k * H_ + j];
      #pragma unroll
      for (int r = 0; r < 8; r++) acc[r] = fmaf(sbuf[(rbase + r) * AD + k], wv2, acc[r]);
    }
    #pragma unroll
    for (int r = 0; r < 8; r++) sh[(rbase + r) * H_ + j] = acc[r] + bi[j];
  }
  __syncthreads();

  float creg[8];
  #pragma unroll
  for (int r = 0; r < 8; r++) creg[r] = 0.f;
  const float bii = b_ih[j] + b_hh[j];
  const float bff = b_ih[j + 512] + b_hh[j + 512];
  const float bgg = b_ih[j + 1024] + b_hh[j + 1024];
  const float boo = b_ih[j + 1536] + b_hh[j + 1536];
  const float bov = bo[t];
  float* cand_v = sbuf;
  int*   cand_i = (int*)(sbuf + 256);

  for (int step = 0; step < L_; step++) {
    float ai[8], af[8], ag2[8], ao[8];
    #pragma unroll
    for (int r = 0; r < 8; r++) { ai[r] = bii; af[r] = bff; ag2[r] = bgg; ao[r] = boo; }
    for (int k = 0; k < DOUT_; k++) {
      float w0 = W_ih[(size_t)j * DOUT_ + k], w1 = W_ih[(size_t)(j + 512) * DOUT_ + k];
      float w2 = W_ih[(size_t)(j + 1024) * DOUT_ + k], w3 = W_ih[(size_t)(j + 1536) * DOUT_ + k];
      #pragma unroll
      for (int r = 0; r < 8; r++) {
        float e = semb[(rbase + r) * DOUT_ + k];
        ai[r] = fmaf(e, w0, ai[r]); af[r] = fmaf(e, w1, af[r]);
        ag2[r] = fmaf(e, w2, ag2[r]); ao[r] = fmaf(e, w3, ao[r]);
      }
    }
    for (int k = 0; k < H_; k++) {
      float w0 = W_hh[(size_t)j * H_ + k], w1 = W_hh[(size_t)(j + 512) * H_ + k];
      float w2 = W_hh[(size_t)(j + 1024) * H_ + k], w3 = W_hh[(size_t)(j + 1536) * H_ + k];
      #pragma unroll
      for (int r = 0; r < 8; r++) {
        float hv = sh[(rbase + r) * H_ + k];
        ai[r] = fmaf(hv, w0, ai[r]); af[r] = fmaf(hv, w1, af[r]);
        ag2[r] = fmaf(hv, w2, ag2[r]); ao[r] = fmaf(hv, w3, ao[r]);
      }
    }
    float hn[8];
    #pragma unroll
    for (int r = 0; r < 8; r++) {
      float iv = 1.f / (1.f + expf(-ai[r]));
      float fv = 1.f / (1.f + expf(-af[r]));
      float gv = tanhf(ag2[r]);
      float ov = 1.f / (1.f + expf(-ao[r]));
      float cn = fv * creg[r] + iv * gv;
      creg[r] = cn;
      hn[r] = ov * tanhf(cn);
    }
    __syncthreads();
    #pragma unroll
    for (int r = 0; r < 8; r++) sh[(rbase + r) * H_ + j] = hn[r];
    __syncthreads();

    float lacc[16];
    #pragma unroll
    for (int r = 0; r < 16; r++) lacc[r] = bov;
    for (int k = 0; k < H_; k++) {
      float wv2 = Wo[(size_t)k * V_ + t];
      #pragma unroll
      for (int r = 0; r < 16; r++) lacc[r] = fmaf(sh[r * H_ + k], wv2, lacc[r]);
    }
    #pragma unroll
    for (int r = 0; r < 16; r++)
      out_logits[((size_t)(r0 + r) * L_ + step) * V_ + t] = lacc[r];
    #pragma unroll
    for (int r = 0; r < 16; r++) {
      float bv = lacc[r]; int bx = t;
      #pragma unroll
      for (int off = 32; off; off >>= 1) {
        float ov = __shfl_xor(bv, off);
        int ox = __shfl_xor(bx, off);
        if (ov > bv || (ov == bv && ox < bx)) { bv = ov; bx = ox; }
      }
      if ((t & 63) == 0) { cand_v[r * 16 + wv] = bv; cand_i[r * 16 + wv] = bx; }
    }
    __syncthreads();
    {
      int r = t >> 6, d = t & 63;
      float bv = cand_v[r * 16]; int bx = cand_i[r * 16];
      #pragma unroll
      for (int c = 1; c < 16; c++) {
        float ov = cand_v[r * 16 + c]; int ox = cand_i[r * 16 + c];
        if (ov > bv || (ov == bv && ox < bx)) { bv = ov; bx = ox; }
      }
      if (d == 0) out_seq[(size_t)(r0 + r) * L_ + step] = (float)bx;
      semb[r * DOUT_ + d] = output_emb[(size_t)bx * DOUT_ + d];
    }
    __syncthreads();
  }
}

extern "C" void kernel_launch(void* const* d_in, const int* in_sizes, int n_in,
                              void* d_out, int out_size, void* d_ws, size_t ws_size,
                              hipStream_t stream) {
  const int*   x          = (const int*)  d_in[0];
  const float* input_emb  = (const float*)d_in[1];
  const float* output_emb = (const float*)d_in[2];
  const float* Wi         = (const float*)d_in[3];
  const float* bi         = (const float*)d_in[4];
  const float* W_ih       = (const float*)d_in[5];
  const float* W_hh       = (const float*)d_in[6];
  const float* b_ih       = (const float*)d_in[7];
  const float* b_hh       = (const float*)d_in[8];
  const float* Wo         = (const float*)d_in[9];
  const float* bo         = (const float*)d_in[10];
  const float* sos        = (const float*)d_in[11];
  float* outp = (float*)d_out;
  float* out_logits = outp + (size_t)B_ * L_;

  // ws layout
  const size_t wg_us   = 2 * GW_HALF;
  const size_t wo_us   = 2 * LW_HALF;
  const size_t hpl_us  = 4 * HPLANE;                   // 2 buffers x (hi,lo)
  const size_t c_f32   = (size_t)B_ * H_;
  const size_t cand_n  = (size_t)B_ * 4;
  const size_t ws_need = (wg_us + wo_us + hpl_us) * sizeof(us)
                       + c_f32 * sizeof(float) + cand_n * 8;   // ~32.1 MB

  if (ws_size >= ws_need) {
    us* WgB   = (us*)d_ws;
    us* WoB   = WgB + wg_us;
    us* h0_hi = WoB + wo_us;
    us* h0_lo = h0_hi + HPLANE;
    us* h1_hi = h0_lo + HPLANE;
    us* h1_lo = h1_hi + HPLANE;
    float* cst    = (float*)(h1_lo + HPLANE);
    float* cand_v = cst + c_f32;
    int*   cand_i = (int*)(cand_v + cand_n);

    us* ph_hi[2] = {h0_hi, h1_hi};
    us* ph_lo[2] = {h0_lo, h1_lo};

    pack_gw<<<(128 * 18 * 64) / 256, 256, 0, stream>>>(W_ih, W_hh, WgB);
    pack_lw<<<(64 * 16 * 64) / 256, 256, 0, stream>>>(Wo, WoB);
    h0_kernel<<<256, 1024, 0, stream>>>(x, input_emb, Wi, bi, h0_hi, h0_lo);

    for (int s = 0; s < L_; s++) {
      int in = s & 1, outb = (s + 1) & 1;
      g_step<<<256, 1024, 0, stream>>>(
          ph_hi[in], ph_lo[in], ph_hi[outb], ph_lo[outb], cst,
          cand_v, cand_i, output_emb, sos, b_ih, b_hh, WgB, outp, s);
      l_step<<<256, 1024, 0, stream>>>(
          ph_hi[outb], ph_lo[outb], WoB, bo, out_logits, cand_v, cand_i, s);
    }
    fin_kernel<<<B_ / 256, 256, 0, stream>>>(cand_v, cand_i, outp);
  } else {
    lstm_fb<<<B_ / 16, 1024, 0, stream>>>(
        x, input_emb, output_emb, Wi, bi, W_ih, W_hh, b_ih, b_hh, Wo, bo, sos, outp);
  }
}

// Round 13
// 2480.112 us; speedup vs baseline: 1.3280x; 1.3280x over previous
//
#include <hip/hip_runtime.h>
#include <math.h>

#define B_    4096
#define A_    6
#define V_    1024
#define L_    32
#define DIN_  64
#define DOUT_ 64
#define H_    512
#define AD    384          // A_*DIN_

typedef unsigned short us;
typedef __attribute__((ext_vector_type(8))) short short8;   // 8 bf16
typedef __attribute__((ext_vector_type(4))) float f32x4;

static constexpr size_t GW_HALF = 128ull * 18 * 512;   // us per split (gates)
static constexpr size_t LW_HALF = 64ull  * 16 * 512;   // us per split (logits)
static constexpr size_t HPLANE  = 4096ull * 512;       // us per h plane

// ---- bf16 helpers (RNE) ----
__device__ __forceinline__ us bfhi(float v) {
  union { float f; unsigned u; } a; a.f = v;
  unsigned r = a.u + 0x7FFFu + ((a.u >> 16) & 1u);
  return (us)(r >> 16);
}
__device__ __forceinline__ float bf2f(us s) {
  union { unsigned u; float f; } a; a.u = (unsigned)s << 16;
  return a.f;
}
__device__ __forceinline__ void bfsplit(float v, us& hi, us& lo) {
  hi = bfhi(v);
  lo = bfhi(v - bf2f(hi));
}
__device__ __forceinline__ int swzE(int m, int k) { return m * 64 + (k ^ ((m & 7) << 3)); }

// async global->LDS, 16B per lane; dest = uniform base + lane*16
__device__ __forceinline__ void gl_lds16(const us* g, us* l) {
  __builtin_amdgcn_global_load_lds(
      (const __attribute__((address_space(1))) unsigned int*)g,
      (__attribute__((address_space(3))) unsigned int*)l, 16, 0, 0);
}

#define MFMA(A, Bv, C) __builtin_amdgcn_mfma_f32_16x16x32_bf16((A), (Bv), (C), 0, 0, 0)

// ---- pack gates: tile = ((js*4+g)*8+jn), kt 0..17 (16 h + 2 emb); kappa(l,e)=(l>>4)*8+e ----
__global__ void pack_gw(const float* __restrict__ W_ih, const float* __restrict__ W_hh,
                        us* __restrict__ WgB) {
  int idx  = blockIdx.x * 256 + threadIdx.x;   // < 128*18*64
  int lane = idx & 63;
  int kt   = (idx >> 6) % 18;
  int tile = idx / (18 * 64);                  // 0..127
  int jn = tile & 7, g = (tile >> 3) & 3, js = tile >> 5;
  int l15 = lane & 15, lg = lane >> 4;
  int gcol = g * 512 + js * 128 + jn * 16 + l15;
  size_t bh = ((size_t)tile * 18 + kt) * 512 + (size_t)lane * 8;
  #pragma unroll
  for (int e = 0; e < 8; e++) {
    int kk = lg * 8 + e;
    float v = (kt < 16) ? W_hh[(size_t)gcol * H_ + kt * 32 + kk]
                        : W_ih[(size_t)gcol * DOUT_ + (kt - 16) * 32 + kk];
    us hi, lo; bfsplit(v, hi, lo);
    WgB[bh + e]           = hi;
    WgB[GW_HALF + bh + e] = lo;
  }
}

// ---- pack Wo[512][1024] -> B-frag tiles (verified layout, vb linear) ----
__global__ void pack_lw(const float* __restrict__ Wo, us* __restrict__ WoB) {
  int idx = blockIdx.x * 256 + threadIdx.x;    // < 64*16*64
  int lane = idx & 63;
  int kt = (idx >> 6) % 16;
  int vb = idx / (16 * 64);
  int l15 = lane & 15, lg = lane >> 4;
  int n = vb * 16 + l15;
  size_t bh = ((size_t)vb * 16 + kt) * 512 + (size_t)lane * 8;
  #pragma unroll
  for (int e = 0; e < 8; e++) {
    int k = kt * 32 + lg * 8 + e;
    us hi, lo; bfsplit(Wo[(size_t)k * V_ + n], hi, lo);
    WoB[bh + e]           = hi;
    WoB[LW_HALF + bh + e] = lo;
  }
}

// ---- prologue: h0 = e @ Wi + bi -> plane0 (bf16 split) ----
__global__ void h0_kernel(const int* __restrict__ x, const float* __restrict__ input_emb,
                          const float* __restrict__ Wi, const float* __restrict__ bi,
                          us* __restrict__ h_hi, us* __restrict__ h_lo) {
  __shared__ float sbuf[16 * AD];
  const int t = threadIdx.x, r0 = blockIdx.x * 16;
  for (int idx = t; idx < 16 * AD; idx += 1024) {
    int r = idx / AD, rem = idx - r * AD;
    sbuf[idx] = input_emb[x[(r0 + r) * A_ + (rem >> 6)] * DIN_ + (rem & 63)];
  }
  __syncthreads();
  int j = t & 511, half = t >> 9;
  float acc[8];
  #pragma unroll
  for (int r = 0; r < 8; r++) acc[r] = 0.f;
  for (int k = 0; k < AD; k++) {
    float wv = Wi[(size_t)k * H_ + j];
    #pragma unroll
    for (int r = 0; r < 8; r++)
      acc[r] = fmaf(sbuf[(half * 8 + r) * AD + k], wv, acc[r]);
  }
  float bj = bi[j];
  #pragma unroll
  for (int r = 0; r < 8; r++) {
    int row = r0 + half * 8 + r;
    us hi, lo; bfsplit(acc[r] + bj, hi, lo);
    h_hi[(size_t)row * H_ + j] = hi;
    h_lo[(size_t)row * H_ + j] = lo;
  }
}

// ---- gates + cell: grid 256 = rg(64) x js(4); block 64 rows x 512 gate-cols ----
// R11 mapping (1 mt x 8 n-tiles) + depth-1 A register prefetch: A(kt+1) global
// loads issue a full kt early, hiding L2 latency under MFMA+LDS of kt.
__launch_bounds__(1024)
__global__ void g_step(
    const us* __restrict__ hin_hi, const us* __restrict__ hin_lo,
    us* __restrict__ hout_hi, us* __restrict__ hout_lo,
    float* __restrict__ cst,
    const float* __restrict__ cand_v, const int* __restrict__ cand_i,
    const float* __restrict__ output_emb, const float* __restrict__ sos,
    const float* __restrict__ b_ih, const float* __restrict__ b_hh,
    const us* __restrict__ WgB,
    float* __restrict__ out_seq, int step)
{
  __shared__ __align__(16) us ldsB[2][32][2][512];   // 128 KB (dbuf x tile x half)
  __shared__ __align__(16) us seA_hi[64 * 64];       // 8 KB
  __shared__ __align__(16) us seA_lo[64 * 64];       // 8 KB

  const int t = threadIdx.x, lane = t & 63, w = t >> 6;
  const int l15 = lane & 15, lg = lane >> 4;
  const int rg = blockIdx.x >> 2, js = blockIdx.x & 3;
  const int r0 = rg * 64;
  const int mt = w & 3, jg = w >> 2;

  // ---- stage kt=0 into buf 0 (each wave: chunks 4w..4w+3) ----
  #pragma unroll
  for (int q = 0; q < 4; q++) {
    int c = w * 4 + q, tl = c >> 1, half = c & 1;
    const us* src = WgB + (size_t)half * GW_HALF
                  + ((size_t)(js * 32 + tl) * 18 + 0) * 512 + (size_t)lane * 8;
    gl_lds16(src, &ldsB[0][tl][half][(size_t)lane * 8]);
  }

  // ---- A(kt=0) register prefetch (no LDS dependency) ----
  const size_t arow = (size_t)(r0 + mt * 16 + l15) * H_;
  short8 nAh = *(const short8*)(hin_hi + arow + lg * 8);
  short8 nAl = *(const short8*)(hin_lo + arow + lg * 8);

  // ---- prologue: winner-merge (step>0) + emb stage ----
  {
    int row = t >> 4;            // 0..63
    int d0  = (t & 15) * 4;
    if (step == 0) {
      #pragma unroll
      for (int dd = 0; dd < 4; dd++) {
        int d = d0 + dd;
        us hi, lo; bfsplit(sos[d], hi, lo);
        int si = swzE(row, d);
        seA_hi[si] = hi; seA_lo[si] = lo;
      }
    } else {
      int grow = r0 + row;
      float bv = cand_v[grow * 4 + 0];
      int   bx = cand_i[grow * 4 + 0];
      #pragma unroll
      for (int c = 1; c < 4; c++) {
        float ov = cand_v[grow * 4 + c];
        int   ox = cand_i[grow * 4 + c];
        if (ov > bv || (ov == bv && ox < bx)) { bv = ov; bx = ox; }
      }
      if (js == 0 && (t & 15) == 0)
        out_seq[(size_t)grow * L_ + (step - 1)] = (float)bx;
      #pragma unroll
      for (int dd = 0; dd < 4; dd++) {
        int d = d0 + dd;
        us hi, lo; bfsplit(output_emb[(size_t)bx * DOUT_ + d], hi, lo);
        int si = swzE(row, d);
        seA_hi[si] = hi; seA_lo[si] = lo;
      }
    }
  }
  __syncthreads();   // seA ready; stage(kt=0) drained (barrier waits vmcnt 0)

  // ---- bias init: acc[g][jt], cols g*512 + js*128 + jg*32 + jt*16 + l15 ----
  f32x4 acc[4][2];
  #pragma unroll
  for (int g = 0; g < 4; g++)
    #pragma unroll
    for (int jt = 0; jt < 2; jt++) {
      int col = g * 512 + js * 128 + jg * 32 + jt * 16 + l15;
      float b = b_ih[col] + b_hh[col];
      acc[g][jt] = (f32x4){b, b, b, b};
    }

  for (int kt = 0; kt < 18; kt++) {
    const int buf = kt & 1;
    if (kt + 1 < 18) {
      #pragma unroll
      for (int q = 0; q < 4; q++) {
        int c = w * 4 + q, tl = c >> 1, half = c & 1;
        const us* src = WgB + (size_t)half * GW_HALF
                      + ((size_t)(js * 32 + tl) * 18 + (kt + 1)) * 512 + (size_t)lane * 8;
        gl_lds16(src, &ldsB[buf ^ 1][tl][half][(size_t)lane * 8]);
      }
    }
    short8 Ah, Al;
    if (kt < 16) {
      Ah = nAh; Al = nAl;
    } else {
      int ai = swzE(mt * 16 + l15, (kt - 16) * 32 + lg * 8);
      Ah = *(const short8*)&seA_hi[ai];
      Al = *(const short8*)&seA_lo[ai];
    }
    if (kt + 1 < 16) {     // prefetch A(kt+1) under this kt's compute
      size_t ko = (size_t)(kt + 1) * 32 + lg * 8;
      nAh = *(const short8*)(hin_hi + arow + ko);
      nAl = *(const short8*)(hin_lo + arow + ko);
    }
    #pragma unroll
    for (int g = 0; g < 4; g++)
      #pragma unroll
      for (int jt = 0; jt < 2; jt++) {
        int tl = g * 8 + jg * 2 + jt;
        short8 Bh = *(const short8*)&ldsB[buf][tl][0][(size_t)lane * 8];
        short8 Bl = *(const short8*)&ldsB[buf][tl][1][(size_t)lane * 8];
        acc[g][jt] = MFMA(Ah, Bh, acc[g][jt]);
        acc[g][jt] = MFMA(Al, Bh, acc[g][jt]);
        acc[g][jt] = MFMA(Ah, Bl, acc[g][jt]);
      }
    __syncthreads();   // readers done with buf; stage(kt+1) complete
  }

  // ---- cell update: row = r0+mt*16+lg*4+reg, j = js*128+jg*32+jt*16+l15 ----
  #pragma unroll
  for (int jt = 0; jt < 2; jt++)
    #pragma unroll
    for (int reg = 0; reg < 4; reg++) {
      int row = r0 + mt * 16 + lg * 4 + reg;
      int j   = js * 128 + jg * 32 + jt * 16 + l15;
      size_t cix = (size_t)row * H_ + j;
      float cprev = (step == 0) ? 0.f : cst[cix];
      float iv = 1.f / (1.f + expf(-acc[0][jt][reg]));
      float fv = 1.f / (1.f + expf(-acc[1][jt][reg]));
      float gv = tanhf(acc[2][jt][reg]);
      float ov = 1.f / (1.f + expf(-acc[3][jt][reg]));
      float cn = fv * cprev + iv * gv;
      cst[cix] = cn;
      us hi, lo; bfsplit(ov * tanhf(cn), hi, lo);
      hout_hi[cix] = hi;
      hout_lo[cix] = lo;
    }
}

// ---- logits + partial argmax: grid 256 = rg(64) x vs(4); block 64 rows x 256 vocab ----
// R11 mapping (1 mt x 4 vt) + 4-deep stage buffers (barrier per 2 kt) +
// depth-1 A register prefetch.
__launch_bounds__(1024)
__global__ void l_step(
    const us* __restrict__ h_hi, const us* __restrict__ h_lo,
    const us* __restrict__ WoB, const float* __restrict__ bo,
    float* __restrict__ out_logits,
    float* __restrict__ cand_v, int* __restrict__ cand_i, int step)
{
  __shared__ __align__(16) us ldsB2[4][16][2][512];  // 128 KB (4 kt buffers)
  __shared__ float cv[64 * 4];
  __shared__ int   ci[64 * 4];

  const int t = threadIdx.x, lane = t & 63, w = t >> 6;
  const int l15 = lane & 15, lg = lane >> 4;
  const int rg = blockIdx.x >> 2, vs = blockIdx.x & 3;
  const int r0 = rg * 64;
  const int mt = w & 3, vg = w >> 2;

  // stage kt=0 -> buf0, kt=1 -> buf1 (each wave: chunks 2w..2w+1)
  #pragma unroll
  for (int kk = 0; kk < 2; kk++)
    #pragma unroll
    for (int q = 0; q < 2; q++) {
      int c = w * 2 + q, tl = c >> 1, half = c & 1;
      const us* src = WoB + (size_t)half * LW_HALF
                    + ((size_t)(vs * 16 + tl) * 16 + kk) * 512 + (size_t)lane * 8;
      gl_lds16(src, &ldsB2[kk][tl][half][(size_t)lane * 8]);
    }
  const size_t arow = (size_t)(r0 + mt * 16 + l15) * H_;
  short8 nAh = *(const short8*)(h_hi + arow + lg * 8);
  short8 nAl = *(const short8*)(h_lo + arow + lg * 8);
  __syncthreads();

  f32x4 acc[4];
  #pragma unroll
  for (int vt = 0; vt < 4; vt++) {
    float b = bo[vs * 256 + vg * 64 + vt * 16 + l15];
    acc[vt] = (f32x4){b, b, b, b};
  }

  for (int kt = 0; kt < 16; kt += 2) {
    // stage kt+2, kt+3 into their (mod-4) buffers
    #pragma unroll
    for (int kk = 0; kk < 2; kk++) {
      int ks = kt + 2 + kk;
      if (ks < 16) {
        #pragma unroll
        for (int q = 0; q < 2; q++) {
          int c = w * 2 + q, tl = c >> 1, half = c & 1;
          const us* src = WoB + (size_t)half * LW_HALF
                        + ((size_t)(vs * 16 + tl) * 16 + ks) * 512 + (size_t)lane * 8;
          gl_lds16(src, &ldsB2[ks & 3][tl][half][(size_t)lane * 8]);
        }
      }
    }
    // compute kt and kt+1
    #pragma unroll
    for (int kk = 0; kk < 2; kk++) {
      int kc = kt + kk;
      short8 Ah = nAh, Al = nAl;
      if (kc + 1 < 16) {   // prefetch A(kc+1) under this kc's compute
        size_t ko = (size_t)(kc + 1) * 32 + lg * 8;
        nAh = *(const short8*)(h_hi + arow + ko);
        nAl = *(const short8*)(h_lo + arow + ko);
      }
      const int bufc = kc & 3;
      #pragma unroll
      for (int vt = 0; vt < 4; vt++) {
        int tl = vg * 4 + vt;
        short8 Bh = *(const short8*)&ldsB2[bufc][tl][0][(size_t)lane * 8];
        short8 Bl = *(const short8*)&ldsB2[bufc][tl][1][(size_t)lane * 8];
        acc[vt] = MFMA(Ah, Bh, acc[vt]);
        acc[vt] = MFMA(Al, Bh, acc[vt]);
        acc[vt] = MFMA(Ah, Bl, acc[vt]);
      }
    }
    __syncthreads();   // readers done with bufs kt,kt+1; stages kt+2,kt+3 complete
  }

  // ---- store logits + per-lane best over vt ----
  float bv[4]; int bx[4];
  #pragma unroll
  for (int reg = 0; reg < 4; reg++) { bv[reg] = acc[0][reg]; bx[reg] = vs * 256 + vg * 64 + l15; }
  #pragma unroll
  for (int vt = 0; vt < 4; vt++) {
    int col = vs * 256 + vg * 64 + vt * 16 + l15;
    #pragma unroll
    for (int reg = 0; reg < 4; reg++) {
      int row = r0 + mt * 16 + lg * 4 + reg;
      float vvl = acc[vt][reg];
      __builtin_nontemporal_store(vvl, &out_logits[((size_t)row * L_ + step) * V_ + col]);
      if (vt > 0 && vvl > bv[reg]) { bv[reg] = vvl; bx[reg] = col; }
    }
  }
  // reduce across the 16 l15 lanes (xor 1,2,4,8) — first-index-wins
  #pragma unroll
  for (int reg = 0; reg < 4; reg++) {
    #pragma unroll
    for (int off = 1; off <= 8; off <<= 1) {
      float ov = __shfl_xor(bv[reg], off);
      int   ox = __shfl_xor(bx[reg], off);
      if (ov > bv[reg] || (ov == bv[reg] && ox < bx[reg])) { bv[reg] = ov; bx[reg] = ox; }
    }
    if (l15 == 0) {
      int rloc = mt * 16 + lg * 4 + reg;
      cv[rloc * 4 + vg] = bv[reg];
      ci[rloc * 4 + vg] = bx[reg];
    }
  }
  __syncthreads();
  if (t < 64) {
    float b2 = cv[t * 4]; int x2 = ci[t * 4];
    #pragma unroll
    for (int c = 1; c < 4; c++) {
      float ov = cv[t * 4 + c]; int ox = ci[t * 4 + c];
      if (ov > b2 || (ov == b2 && ox < x2)) { b2 = ov; x2 = ox; }
    }
    cand_v[(size_t)(r0 + t) * 4 + vs] = b2;
    cand_i[(size_t)(r0 + t) * 4 + vs] = x2;
  }
}

// ---- final: merge step-31 candidates -> seq col 31 ----
__global__ void fin_kernel(const float* __restrict__ cand_v, const int* __restrict__ cand_i,
                           float* __restrict__ out_seq) {
  int row = blockIdx.x * 256 + threadIdx.x;
  float bv = cand_v[(size_t)row * 4];
  int   bx = cand_i[(size_t)row * 4];
  #pragma unroll
  for (int c = 1; c < 4; c++) {
    float ov = cand_v[(size_t)row * 4 + c];
    int   ox = cand_i[(size_t)row * 4 + c];
    if (ov > bv || (ov == bv && ox < bx)) { bv = ov; bx = ox; }
  }
  out_seq[(size_t)row * L_ + 31] = (float)bx;
}

// ---------------- fp32 single-kernel fallback (ws too small) ----------------
__launch_bounds__(1024)
__global__ void lstm_fb(
    const int* __restrict__ x, const float* __restrict__ input_emb,
    const float* __restrict__ output_emb, const float* __restrict__ Wi,
    const float* __restrict__ bi, const float* __restrict__ W_ih,
    const float* __restrict__ W_hh, const float* __restrict__ b_ih,
    const float* __restrict__ b_hh, const float* __restrict__ Wo,
    const float* __restrict__ bo, const float* __restrict__ sos,
    float* __restrict__ out)
{
  __shared__ __align__(16) float sh[16 * H_];
  __shared__ __align__(16) float semb[16 * DOUT_];
  __shared__ __align__(16) float sbuf[16 * AD];

  const int t = threadIdx.x, r0 = blockIdx.x * 16;
  const int j = t & 511, rbase = (t >> 9) * 8, wv = t >> 6;
  float* out_seq = out;
  float* out_logits = out + (size_t)B_ * L_;

  for (int idx = t; idx < 16 * AD; idx += 1024) {
    int r = idx / AD, rem = idx - r * AD;
    sbuf[idx] = input_emb[x[(r0 + r) * A_ + (rem >> 6)] * DIN_ + (rem & 63)];
  }
  for (int idx = t; idx < 16 * DOUT_; idx += 1024) semb[idx] = sos[idx & 63];
  __syncthreads();
  {
    float acc[8];
    #pragma unroll
    for (int r = 0; r < 8; r++) acc[r] = 0.f;
    for (int k = 0; k < AD; k++) {
      float wv2 = Wi[(size_t)k * H_ + j];
      #pragma unroll
      for (int r = 0; r < 8; r++) acc[r] = fmaf(sbuf[(rbase + r) * AD + k], wv2, acc[r]);
    }
    #pragma unroll
    for (int r = 0; r < 8; r++) sh[(rbase + r) * H_ + j] = acc[r] + bi[j];
  }
  __syncthreads();

  float creg[8];
  #pragma unroll
  for (int r = 0; r < 8; r++) creg[r] = 0.f;
  const float bii = b_ih[j] + b_hh[j];
  const float bff = b_ih[j + 512] + b_hh[j + 512];
  const float bgg = b_ih[j + 1024] + b_hh[j + 1024];
  const float boo = b_ih[j + 1536] + b_hh[j + 1536];
  const float bov = bo[t];
  float* cand_v = sbuf;
  int*   cand_i = (int*)(sbuf + 256);

  for (int step = 0; step < L_; step++) {
    float ai[8], af[8], ag2[8], ao[8];
    #pragma unroll
    for (int r = 0; r < 8; r++) { ai[r] = bii; af[r] = bff; ag2[r] = bgg; ao[r] = boo; }
    for (int k = 0; k < DOUT_; k++) {
      float w0 = W_ih[(size_t)j * DOUT_ + k], w1 = W_ih[(size_t)(j + 512) * DOUT_ + k];
      float w2 = W_ih[(size_t)(j + 1024) * DOUT_ + k], w3 = W_ih[(size_t)(j + 1536) * DOUT_ + k];
      #pragma unroll
      for (int r = 0; r < 8; r++) {
        float e = semb[(rbase + r) * DOUT_ + k];
        ai[r] = fmaf(e, w0, ai[r]); af[r] = fmaf(e, w1, af[r]);
        ag2[r] = fmaf(e, w2, ag2[r]); ao[r] = fmaf(e, w3, ao[r]);
      }
    }
    for (int k = 0; k < H_; k++) {
      float w0 = W_hh[(size_t)j * H_ + k], w1 = W_hh[(size_t)(j + 512) * H_ + k];
      float w2 = W_hh[(size_t)(j + 1024) * H_ + k], w3 = W_hh[(size_t)(j + 1536) * H_ + k];
      #pragma unroll
      for (int r = 0; r < 8; r++) {
        float hv = sh[(rbase + r) * H_ + k];
        ai[r] = fmaf(hv, w0, ai[r]); af[r] = fmaf(hv, w1, af[r]);
        ag2[r] = fmaf(hv, w2, ag2[r]); ao[r] = fmaf(hv, w3, ao[r]);
      }
    }
    float hn[8];
    #pragma unroll
    for (int r = 0; r < 8; r++) {
      float iv = 1.f / (1.f + expf(-ai[r]));
      float fv = 1.f / (1.f + expf(-af[r]));
      float gv = tanhf(ag2[r]);
      float ov = 1.f / (1.f + expf(-ao[r]));
      float cn = fv * creg[r] + iv * gv;
      creg[r] = cn;
      hn[r] = ov * tanhf(cn);
    }
    __syncthreads();
    #pragma unroll
    for (int r = 0; r < 8; r++) sh[(rbase + r) * H_ + j] = hn[r];
    __syncthreads();

    float lacc[16];
    #pragma unroll
    for (int r = 0; r < 16; r++) lacc[r] = bov;
    for (int k = 0; k < H_; k++) {
      float wv2 = Wo[(size_t)k * V_ + t];
      #pragma unroll
      for (int r = 0; r < 16; r++) lacc[r] = fmaf(sh[r * H_ + k], wv2, lacc[r]);
    }
    #pragma unroll
    for (int r = 0; r < 16; r++)
      out_logits[((size_t)(r0 + r) * L_ + step) * V_ + t] = lacc[r];
    #pragma unroll
    for (int r = 0; r < 16; r++) {
      float bv = lacc[r]; int bx = t;
      #pragma unroll
      for (int off = 32; off; off >>= 1) {
        float ov = __shfl_xor(bv, off);
        int ox = __shfl_xor(bx, off);
        if (ov > bv || (ov == bv && ox < bx)) { bv = ov; bx = ox; }
      }
      if ((t & 63) == 0) { cand_v[r * 16 + wv] = bv; cand_i[r * 16 + wv] = bx; }
    }
    __syncthreads();
    {
      int r = t >> 6, d = t & 63;
      float bv = cand_v[r * 16]; int bx = cand_i[r * 16];
      #pragma unroll
      for (int c = 1; c < 16; c++) {
        float ov = cand_v[r * 16 + c]; int ox = cand_i[r * 16 + c];
        if (ov > bv || (ov == bv && ox < bx)) { bv = ov; bx = ox; }
      }
      if (d == 0) out_seq[(size_t)(r0 + r) * L_ + step] = (float)bx;
      semb[r * DOUT_ + d] = output_emb[(size_t)bx * DOUT_ + d];
    }
    __syncthreads();
  }
}

extern "C" void kernel_launch(void* const* d_in, const int* in_sizes, int n_in,
                              void* d_out, int out_size, void* d_ws, size_t ws_size,
                              hipStream_t stream) {
  const int*   x          = (const int*)  d_in[0];
  const float* input_emb  = (const float*)d_in[1];
  const float* output_emb = (const float*)d_in[2];
  const float* Wi         = (const float*)d_in[3];
  const float* bi         = (const float*)d_in[4];
  const float* W_ih       = (const float*)d_in[5];
  const float* W_hh       = (const float*)d_in[6];
  const float* b_ih       = (const float*)d_in[7];
  const float* b_hh       = (const float*)d_in[8];
  const float* Wo         = (const float*)d_in[9];
  const float* bo         = (const float*)d_in[10];
  const float* sos        = (const float*)d_in[11];
  float* outp = (float*)d_out;
  float* out_logits = outp + (size_t)B_ * L_;

  // ws layout
  const size_t wg_us   = 2 * GW_HALF;
  const size_t wo_us   = 2 * LW_HALF;
  const size_t hpl_us  = 4 * HPLANE;                   // 2 buffers x (hi,lo)
  const size_t c_f32   = (size_t)B_ * H_;
  const size_t cand_n  = (size_t)B_ * 4;
  const size_t ws_need = (wg_us + wo_us + hpl_us) * sizeof(us)
                       + c_f32 * sizeof(float) + cand_n * 8;   // ~32.1 MB

  if (ws_size >= ws_need) {
    us* WgB   = (us*)d_ws;
    us* WoB   = WgB + wg_us;
    us* h0_hi = WoB + wo_us;
    us* h0_lo = h0_hi + HPLANE;
    us* h1_hi = h0_lo + HPLANE;
    us* h1_lo = h1_hi + HPLANE;
    float* cst    = (float*)(h1_lo + HPLANE);
    float* cand_v = cst + c_f32;
    int*   cand_i = (int*)(cand_v + cand_n);

    us* ph_hi[2] = {h0_hi, h1_hi};
    us* ph_lo[2] = {h0_lo, h1_lo};

    pack_gw<<<(128 * 18 * 64) / 256, 256, 0, stream>>>(W_ih, W_hh, WgB);
    pack_lw<<<(64 * 16 * 64) / 256, 256, 0, stream>>>(Wo, WoB);
    h0_kernel<<<256, 1024, 0, stream>>>(x, input_emb, Wi, bi, h0_hi, h0_lo);

    for (int s = 0; s < L_; s++) {
      int in = s & 1, outb = (s + 1) & 1;
      g_step<<<256, 1024, 0, stream>>>(
          ph_hi[in], ph_lo[in], ph_hi[outb], ph_lo[outb], cst,
          cand_v, cand_i, output_emb, sos, b_ih, b_hh, WgB, outp, s);
      l_step<<<256, 1024, 0, stream>>>(
          ph_hi[outb], ph_lo[outb], WoB, bo, out_logits, cand_v, cand_i, s);
    }
    fin_kernel<<<B_ / 256, 256, 0, stream>>>(cand_v, cand_i, outp);
  } else {
    lstm_fb<<<B_ / 16, 1024, 0, stream>>>(
        x, input_emb, output_emb, Wi, bi, W_ih, W_hh, b_ih, b_hh, Wo, bo, sos, outp);
  }
}